// Round 12
// baseline (79.699 us; speedup 1.0000x reference)
//
#include <hip/hip_runtime.h>

// RWKV-4 WKV forward. B=16, T=1024, C=2048, fp32.
// T-split chunked scan (z-space) + 2-slot LDS-ring streaming, sized for
// 4 blocks/CU (LDS 39,680 B <= 40,960): CHUNK=4, SEG=32, NSEG=32,
// single-buffered T (2 barriers/segment), direct non-temporal y stores,
// refill of slot (s&1) issued right after the z-phase consumes it.
// vmcnt audit (per-wave FIFO; 2 w16 loads mid-seg + 4 nt stores end-seg):
//   newer-than-L_s at top-of-segment wait:
//     s==0: L_1(2) = 2
//     s==1: L_2(2) + st_0(4) = 6
//     2<=s<=30: st_{s-2}(4) + L_{s+1}(2) + st_{s-1}(4) = 10
//     s==31: st_29(4) + st_30(4) = 8
// Barrier audit (2 per segment, T single-buffered):
//   barrier A: T writes (pre-A, drained by lgkmcnt(0)) -> compose reads.
//   barrier B: compose reads done -> T writable in seg s+1; S[1-sl] write
//   (post-A) drained by writer's lgkmcnt(0) before B; read after next A.
// Cross-wave LDS k/v safety: each wave DMAs and reads ONLY its own rows.

#define T_DIM 1024
#define CDIM  2048
#define CHUNK 4
#define WAVES 8
#define SEG   (WAVES * CHUNK)   // 32
#define NSEG  (T_DIM / SEG)     // 32
#define NEG_BIG -1e38f

typedef const __attribute__((address_space(1))) float* gp_t;
typedef __attribute__((address_space(3))) float* lp_t;

__global__ __launch_bounds__(WAVES * 64, 4) void wkv_fwd_kernel(
    const float* __restrict__ w, const float* __restrict__ u,
    const float* __restrict__ kk, const float* __restrict__ vv,
    float* __restrict__ y)
{
    __shared__ __align__(16) float lk[2][SEG][64];               // 16 KB
    __shared__ __align__(16) float lv[2][SEG][64];               // 16 KB
    __shared__ float Tp[WAVES-1][64], Tq[WAVES-1][64], To[WAVES-1][64]; // 5.25 KB
    __shared__ float Sp[2][64], Sq[2][64], So[2][64];            // 1.5 KB

    const int lane = threadIdx.x & 63;
    const int wid  = threadIdx.x >> 6;
    const int b    = blockIdx.y;
    const int c0   = blockIdx.x * 64;

    const float wc  = w[c0 + lane];
    const float uc  = u[c0 + lane];
    const float wCH = wc * (float)CHUNK;

    const size_t sbase = (size_t)b * T_DIM * CDIM + c0;  // slab base (t=0)
    const int rl = lane >> 4;           // row within 4-row group
    const int cl = (lane & 15) * 4;     // col dword
    const float* kgl = kk + sbase + (size_t)rl * CDIM + cl;
    const float* vgl = vv + sbase + (size_t)rl * CDIM + cl;
    float*       yp  = y  + sbase + lane;   // + t*CDIM

    if (wid == 0) { Sp[0][lane] = 0.f; Sq[0][lane] = 0.f; So[0][lane] = NEG_BIG; }

    // issue this wave's 4 rows of one segment: 1 k-load + 1 v-load (w16)
    auto issue_seg = [&](int s) {
        const int sl = s & 1;
        const size_t go = (size_t)(s * SEG + wid * CHUNK) * CDIM;
        __builtin_amdgcn_global_load_lds((gp_t)(kgl + go),
            (lp_t)&lk[sl][wid * CHUNK][0], 16, 0, 0);
        __builtin_amdgcn_global_load_lds((gp_t)(vgl + go),
            (lp_t)&lv[sl][wid * CHUNK][0], 16, 0, 0);
    };

    issue_seg(0);
    issue_seg(1);

#pragma unroll 1
    for (int s = 0; s < NSEG; ++s) {
        const int sl = s & 1;

        // wait for MY segment-s loads (exact FIFO counts, audit above)
        if (s == 0)            asm volatile("s_waitcnt vmcnt(2)"  ::: "memory");
        else if (s == 1)       asm volatile("s_waitcnt vmcnt(6)"  ::: "memory");
        else if (s == NSEG-1)  asm volatile("s_waitcnt vmcnt(8)"  ::: "memory");
        else                   asm volatile("s_waitcnt vmcnt(10)" ::: "memory");
        __builtin_amdgcn_sched_barrier(0);

        // z-space precompute from LDS slot sl (own rows only)
        float uk[CHUNK], hh[CHUNK], cf[CHUNK], df[CHUNK], vc[CHUNK];
        float M = NEG_BIG;
#pragma unroll
        for (int j = 0; j < CHUNK; ++j) {
            const float kt = lk[sl][wid * CHUNK + j][lane];
            vc[j] = lv[sl][wid * CHUNK + j][lane];
            const float zj = fmaf((float)(-j), wc, kt);   // k_j - j*w
            uk[j] = uc + kt;
            const float dl = M - zj;
            cf[j] = __expf(fminf(dl, 0.f));
            df[j] = __expf(fminf(-dl, 0.f));
            hh[j] = fmaf((float)(j - 1), wc, M);
            M = fmaxf(M, zj);
        }
        float Pt = 0.f, Qt = 0.f;
#pragma unroll
        for (int j = 0; j < CHUNK; ++j) {
            Pt = fmaf(cf[j], Pt, df[j] * vc[j]);
            Qt = fmaf(cf[j], Qt, df[j]);
        }

        // slot sl fully consumed into registers -> refill it for seg s+2
        asm volatile("s_waitcnt lgkmcnt(0)" ::: "memory");
        __builtin_amdgcn_sched_barrier(0);
        if (s + 2 < NSEG) issue_seg(s + 2);

        if (wid < WAVES - 1) {
            Tp[wid][lane] = Pt; Tq[wid][lane] = Qt;
            To[wid][lane] = fmaf((float)(CHUNK - 1), wc, M);
        }

        // barrier A: T(s) visible; vmem stays in flight
        asm volatile("s_waitcnt lgkmcnt(0)" ::: "memory");
        __builtin_amdgcn_s_barrier();

        // compose S_in = S_run ∘ T_0 ∘ ... ∘ T_{wid-1}
        float p = Sp[sl][lane], q = Sq[sl][lane], o = So[sl][lane];
        for (int j = 0; j < wid; ++j) {       // wave-uniform trip count
            const float Oj = To[j][lane];
            const float a  = o + wCH;
            const float d  = a - Oj;
            const float e  = __expf(-fabsf(d));
            const float sA = d >= 0.f ? 1.f : e;
            const float sB = d >= 0.f ? e : 1.f;
            p = fmaf(sA, p, sB * Tp[j][lane]);
            q = fmaf(sA, q, sB * Tq[j][lane]);
            o = fmaxf(a, Oj);
        }

        // new running state (compose result + own totals)
        if (wid == WAVES - 1) {
            const float Ot = fmaf((float)(CHUNK - 1), wc, M);
            const float a  = o + wCH;
            const float d  = a - Ot;
            const float e  = __expf(-fabsf(d));
            const float sA = d >= 0.f ? 1.f : e;
            const float sB = d >= 0.f ? e : 1.f;
            Sp[1 - sl][lane] = fmaf(sA, p, sB * Pt);
            Sq[1 - sl][lane] = fmaf(sA, q, sB * Qt);
            So[1 - sl][lane] = fmaxf(a, Ot);
        }

        // barrier B: all compose reads of T done -> T writable next segment
        asm volatile("s_waitcnt lgkmcnt(0)" ::: "memory");
        __builtin_amdgcn_s_barrier();

        // y loop: exact per-step normalizer; direct NON-TEMPORAL stores
        const int tb = s * SEG + wid * CHUNK;
        float aP = 0.f, aQ = 0.f;
#pragma unroll
        for (int j = 0; j < CHUNK; ++j) {
            const float g   = fmaf((float)j, wc, o);
            const float no  = fmaxf(fmaxf(g, hh[j]), uk[j]);
            const float ea  = __expf(g - no);
            const float eb  = __expf(hh[j] - no);
            const float ec  = __expf(uk[j] - no);
            const float num = fmaf(ea, p, fmaf(eb, aP, ec * vc[j]));
            const float den = fmaf(ea, q, fmaf(eb, aQ, ec));
            __builtin_nontemporal_store(__fdividef(num, den),
                                        yp + (size_t)(tb + j) * CDIM);
            aP = fmaf(cf[j], aP, df[j] * vc[j]);
            aQ = fmaf(cf[j], aQ, df[j]);
        }
    }
}

extern "C" void kernel_launch(void* const* d_in, const int* in_sizes, int n_in,
                              void* d_out, int out_size, void* d_ws, size_t ws_size,
                              hipStream_t stream) {
    // inputs: 0=B, 1=T, 2=C (scalars), 3=w[C], 4=u[C], 5=k[B*T*C], 6=v[B*T*C]
    const float* w = (const float*)d_in[3];
    const float* u = (const float*)d_in[4];
    const float* k = (const float*)d_in[5];
    const float* v = (const float*)d_in[6];
    float* y = (float*)d_out;

    const int B = in_sizes[5] / (T_DIM * CDIM);   // 16

    dim3 grid(CDIM / 64, B);
    dim3 block(WAVES * 64);
    wkv_fwd_kernel<<<grid, block, 0, stream>>>(w, u, k, v, y);
}